// Round 6
// baseline (386.071 us; speedup 1.0000x reference)
//
#include <hip/hip_runtime.h>
#include <hip/hip_bf16.h>
#include <math.h>

// N=100000 nodes, E=600000 edges, F=H=128, B=250 graphs, 400 nodes/graph.
//
// Pipeline (all h interfaces bf16, fp32 accumulation):
//   count -> prep (x->bf16 + dinv + cluster) -> deghist/degscan/order (degree
//   buckets) -> scan -> fill (CSR with (col,w) int2)
//   3x { agg: ab = (D^-1/2 (A+I) D^-1/2) hb   (degree-uniform waves, unroll-2)
//        gemm_mfma: hb = [relu](ab @ W + b)   (LDS-staged Wt, 16x16x32 MFMA) }
//   pool_part (16 partials/graph, bf16 reads) + head
//
// R1: pool 113us @5% occ -> 16 partials/graph. 671->572.
// R2: agg gather-byte bound -> bf16 gathers.
// R3: fp32 SIMT gemm 126us -> MFMA bf16, bf16-only h. 688->436.
// R4: agg 4 nodes/wave + edge weights; gemm LDS-staged Wt. 436->354.
// R5: agg still latency-bound (~35us, 2.5TB/s): (a) degree-bucketed order ->
//     no divergence (Poisson max-of-4 cost ~31%); (b) unroll-2 -> 2 gathers
//     in flight per group. Predicted agg ~20us each.

#define WAVE 64
#define NPARTS 16
#define WPAD 136   // padded LDS row stride (ushorts) for conflict-free ds_read_b128

typedef __attribute__((ext_vector_type(8))) short bf16x8;
typedef __attribute__((ext_vector_type(4))) float f32x4;

__device__ __forceinline__ float bflo(unsigned u) { return __uint_as_float(u << 16); }
__device__ __forceinline__ float bfhi(unsigned u) { return __uint_as_float(u & 0xffff0000u); }
__device__ __forceinline__ float bfs(unsigned short s) {
    return __uint_as_float(((unsigned)s) << 16);
}
__device__ __forceinline__ unsigned short bf16r(float f) {
    unsigned u = __float_as_uint(f);
    return (unsigned short)((u + 0x7fffu + ((u >> 16) & 1u)) >> 16);
}
__device__ __forceinline__ unsigned pack_bf16(float a, float b) {
    return (unsigned)bf16r(a) | ((unsigned)bf16r(b) << 16);
}
__device__ __forceinline__ void fma8(float* acc, float w, uint4 u) {
    acc[0] += w * bflo(u.x); acc[1] += w * bfhi(u.x);
    acc[2] += w * bflo(u.y); acc[3] += w * bfhi(u.y);
    acc[4] += w * bflo(u.z); acc[5] += w * bfhi(u.z);
    acc[6] += w * bflo(u.w); acc[7] += w * bfhi(u.w);
}

// ---------------- CSR build ----------------

__global__ void count_kernel(const int* __restrict__ dst, int* __restrict__ cnt, int ne) {
    int e = blockIdx.x * blockDim.x + threadIdx.x;
    if (e < ne) atomicAdd(&cnt[dst[e]], 1);
}

// fused: x -> bf16, plus per-row dinv and cluster (one pass over x)
__global__ void prep_kernel(const float* __restrict__ x, unsigned* __restrict__ hb,
                            const int* __restrict__ cnt, float* __restrict__ dinv,
                            int* __restrict__ cluster, int n32) {
    int i = blockIdx.x * blockDim.x + threadIdx.x;   // handles 4 floats
    if (i >= n32) return;
    float4 v = ((const float4*)x)[i];
    hb[i * 2 + 0] = pack_bf16(v.x, v.y);
    hb[i * 2 + 1] = pack_bf16(v.z, v.w);
    if ((i & 31) == 31) {                            // floats 124..127 of this row
        int row = i >> 5;
        dinv[row] = rsqrtf((float)(cnt[row] + 1));
        cluster[row] = (int)(v.w + 2.0f * v.z + 0.5f);
    }
}

// ---- degree-bucket ordering: nodes grouped by degree so waves are uniform ----

__global__ void deghist(const int* __restrict__ cnt, int* __restrict__ degcnt, int n) {
    __shared__ int lbin[64];
    int t = threadIdx.x;
    if (t < 64) lbin[t] = 0;
    __syncthreads();
    int i = blockIdx.x * 256 + t;
    if (i < n) atomicAdd(&lbin[min(cnt[i], 63)], 1);
    __syncthreads();
    if (t < 64 && lbin[t]) atomicAdd(&degcnt[t], lbin[t]);
}

__global__ void degscan(const int* __restrict__ degcnt, int* __restrict__ degbase) {
    __shared__ int lds[64];
    int t = threadIdx.x;   // 64 threads
    lds[t] = degcnt[t];
    __syncthreads();
    if (t == 0) {
        int s = 0;
        for (int i = 0; i < 64; ++i) { int c = lds[i]; lds[i] = s; s += c; }
    }
    __syncthreads();
    degbase[t] = lds[t];
}

__global__ void order_kernel(const int* __restrict__ cnt, const int* __restrict__ degbase,
                             int* __restrict__ degfill, int* __restrict__ order, int n) {
    __shared__ int lbin[64];
    __shared__ int lbase[64];
    int t = threadIdx.x;
    if (t < 64) lbin[t] = 0;
    __syncthreads();
    int i = blockIdx.x * 256 + t;
    int d = 0, rank = 0;
    if (i < n) {
        d = min(cnt[i], 63);
        rank = atomicAdd(&lbin[d], 1);
    }
    __syncthreads();
    if (t < 64) {
        int c = lbin[t];
        lbase[t] = c ? atomicAdd(&degfill[t], c) : 0;
    }
    __syncthreads();
    if (i < n) order[degbase[d] + lbase[d] + rank] = i;
}

// exclusive scan of cnt -> row_ptr, 1024 elements per block
__global__ void scan_block(const int* __restrict__ in, int* __restrict__ out,
                           int* __restrict__ bsums, int n) {
    __shared__ int lds[256];
    int t = threadIdx.x;
    int base = blockIdx.x * 1024 + t * 4;
    int v0 = (base + 0 < n) ? in[base + 0] : 0;
    int v1 = (base + 1 < n) ? in[base + 1] : 0;
    int v2 = (base + 2 < n) ? in[base + 2] : 0;
    int v3 = (base + 3 < n) ? in[base + 3] : 0;
    int s = v0 + v1 + v2 + v3;
    lds[t] = s;
    __syncthreads();
    for (int off = 1; off < 256; off <<= 1) {
        int add = (t >= off) ? lds[t - off] : 0;
        __syncthreads();
        lds[t] += add;
        __syncthreads();
    }
    int excl = lds[t] - s;
    if (base + 0 < n) out[base + 0] = excl;
    if (base + 1 < n) out[base + 1] = excl + v0;
    if (base + 2 < n) out[base + 2] = excl + v0 + v1;
    if (base + 3 < n) out[base + 3] = excl + v0 + v1 + v2;
    if (t == 255) bsums[blockIdx.x] = lds[255];
}

__global__ void scan_bsums(int* __restrict__ bsums, int nb) {
    __shared__ int lds[256];
    int t = threadIdx.x;
    int v = (t < nb) ? bsums[t] : 0;
    lds[t] = v;
    __syncthreads();
    for (int off = 1; off < 256; off <<= 1) {
        int add = (t >= off) ? lds[t - off] : 0;
        __syncthreads();
        lds[t] += add;
        __syncthreads();
    }
    if (t < nb) bsums[t] = lds[t] - v;   // exclusive
}

__global__ void scan_add(int* __restrict__ out, const int* __restrict__ bsums, int n) {
    int base = blockIdx.x * 1024 + threadIdx.x * 4;
    int add = bsums[blockIdx.x];
#pragma unroll
    for (int i = 0; i < 4; ++i)
        if (base + i < n) out[base + i] += add;
}

// CSR fill with precomputed edge weight: ce[pos] = (src, dinv[src]*dinv[dst])
__global__ void fill_kernel(const int* __restrict__ src, const int* __restrict__ dst,
                            const int* __restrict__ row_ptr, int* __restrict__ fill,
                            int2* __restrict__ ce, const float* __restrict__ dinv,
                            int ne) {
    int e = blockIdx.x * blockDim.x + threadIdx.x;
    if (e < ne) {
        int d = dst[e], s = src[e];
        int pos = row_ptr[d] + atomicAdd(&fill[d], 1);
        ce[pos] = make_int2(s, __float_as_int(dinv[s] * dinv[d]));
    }
}

// ---------------- aggregation: 4 degree-matched nodes/wave, unroll-2 ----------
// out[n][:] = dinv[n]^2 * hb[n][:] + sum_{(s,w) in CSR(n)} w * hb[s][:]

__global__ void agg_kernel(const uint4* __restrict__ hb4, uint4* __restrict__ out4,
                           const int* __restrict__ row_ptr, const int* __restrict__ cnt,
                           const int2* __restrict__ ce, const float* __restrict__ dinv,
                           const int* __restrict__ order, int n) {
    int wid = blockIdx.x * (blockDim.x >> 6) + (threadIdx.x >> 6);
    int lane = threadIdx.x & 63;
    int g = lane >> 4, sl = lane & 15;     // group (node slot) and sublane
    int idx = wid * 4 + g;
    bool ok = idx < n;
    int node = order[ok ? idx : (n - 1)];
    float di = dinv[node];
    uint4 self = hb4[(size_t)node * 16 + sl];
    float w0 = di * di;
    float acc[8];
    acc[0] = w0 * bflo(self.x); acc[1] = w0 * bfhi(self.x);
    acc[2] = w0 * bflo(self.y); acc[3] = w0 * bfhi(self.y);
    acc[4] = w0 * bflo(self.z); acc[5] = w0 * bfhi(self.z);
    acc[6] = w0 * bflo(self.w); acc[7] = w0 * bfhi(self.w);
    int s0 = row_ptr[node];
    int deg = ok ? cnt[node] : 0;
    int2 cw0 = (deg > 0) ? ce[s0] : make_int2(0, 0);
    int2 cw1 = (deg > 1) ? ce[s0 + 1] : cw0;
    int i = 0;
    for (; i + 2 <= deg; i += 2) {
        int2 n0 = (i + 2 < deg) ? ce[s0 + i + 2] : cw0;   // prefetch pair
        int2 n1 = (i + 3 < deg) ? ce[s0 + i + 3] : cw1;
        uint4 u0 = hb4[(size_t)cw0.x * 16 + sl];          // 2 gathers in flight
        uint4 u1 = hb4[(size_t)cw1.x * 16 + sl];
        fma8(acc, __int_as_float(cw0.y), u0);
        fma8(acc, __int_as_float(cw1.y), u1);
        cw0 = n0; cw1 = n1;
    }
    if (i < deg) {
        uint4 u = hb4[(size_t)cw0.x * 16 + sl];
        fma8(acc, __int_as_float(cw0.y), u);
    }
    if (ok) {
        uint4 o;
        o.x = pack_bf16(acc[0], acc[1]);
        o.y = pack_bf16(acc[2], acc[3]);
        o.z = pack_bf16(acc[4], acc[5]);
        o.w = pack_bf16(acc[6], acc[7]);
        out4[(size_t)node * 16 + sl] = o;
    }
}

// ---------------- MFMA bf16 GEMM: Cb[M][128] = [relu](A[M][128] @ W + b) -------------

__global__ __launch_bounds__(256) void gemm_mfma(const unsigned short* __restrict__ A,
                                                 const unsigned short* __restrict__ Wt,
                                                 const float* __restrict__ bias,
                                                 unsigned short* __restrict__ Cb,
                                                 int relu) {
    __shared__ unsigned short sm[128 * WPAD];   // 34816 B; reused as epilogue staging
    const int t = threadIdx.x;
    const int wave = t >> 6, lane = t & 63;
    const int quad = lane >> 4, lr = lane & 15;
    const size_t row0 = (size_t)blockIdx.x * 128 + wave * 32;

    {
        int r = t >> 1, h = t & 1;
        const uint4* s = (const uint4*)(Wt + r * 128 + h * 64);
        uint4* d = (uint4*)(sm + r * WPAD + h * 64);
#pragma unroll
        for (int i = 0; i < 8; ++i) d[i] = s[i];
    }
    __syncthreads();

    f32x4 acc[2][8];
#pragma unroll
    for (int i2 = 0; i2 < 2; ++i2)
#pragma unroll
        for (int ct = 0; ct < 8; ++ct) acc[i2][ct] = (f32x4){0.f, 0.f, 0.f, 0.f};

    const unsigned short* arow0 = A + (row0 + lr) * 128;
    const unsigned short* arow1 = arow0 + 16 * 128;
#pragma unroll
    for (int kc = 0; kc < 4; ++kc) {
        int kb = kc * 32 + quad * 8;
        bf16x8 a0 = *(const bf16x8*)(arow0 + kb);
        bf16x8 a1 = *(const bf16x8*)(arow1 + kb);
#pragma unroll
        for (int ct = 0; ct < 8; ++ct) {
            bf16x8 b = *(const bf16x8*)(sm + (ct * 16 + lr) * WPAD + kb);
            acc[0][ct] = __builtin_amdgcn_mfma_f32_16x16x32_bf16(a0, b, acc[0][ct], 0, 0, 0);
            acc[1][ct] = __builtin_amdgcn_mfma_f32_16x16x32_bf16(a1, b, acc[1][ct], 0, 0, 0);
        }
    }
    __syncthreads();   // all waves done reading sm -> reuse as output staging

    unsigned short* sOut = sm + wave * 4096;
#pragma unroll
    for (int ct = 0; ct < 8; ++ct) {
        float bs = bias[ct * 16 + lr];
#pragma unroll
        for (int i2 = 0; i2 < 2; ++i2)
#pragma unroll
            for (int i = 0; i < 4; ++i) {
                float v = acc[i2][ct][i] + bs;
                if (relu) v = fmaxf(v, 0.f);
                sOut[(i2 * 16 + quad * 4 + i) * 128 + ct * 16 + lr] = bf16r(v);
            }
    }
    __syncthreads();
    const uint4* srcv = (const uint4*)sOut;
    uint4* dstv = (uint4*)(Cb + row0 * 128);
#pragma unroll
    for (int it = 0; it < 8; ++it)
        dstv[it * 64 + lane] = srcv[it * 64 + lane];
}

// all 3 layers: W[k][n] fp32 -> Wt[n][k] bf16
__global__ void wtrans3(const float* __restrict__ W1, const float* __restrict__ W2,
                        const float* __restrict__ W3, unsigned short* __restrict__ Wt) {
    int idx = (blockIdx.x & 63) * 256 + threadIdx.x;   // 0..16383
    int layer = blockIdx.x >> 6;
    const float* W = (layer == 0) ? W1 : (layer == 1) ? W2 : W3;
    int n = idx >> 7, k = idx & 127;
    Wt[layer * 16384 + n * 128 + k] = bf16r(W[k * 128 + n]);
}

// ---------------- pooling: 16 partial blocks per graph, bf16 reads ----------------

__global__ void pool_part(const unsigned short* __restrict__ h,
                          const int* __restrict__ cluster,
                          float* __restrict__ part_sums, int* __restrict__ part_cnts,
                          int npg) {
    int blk = blockIdx.x;
    int g = blk / NPARTS, p = blk % NPARTS;
    int j = threadIdx.x;
    int per = npg / NPARTS;
    int base = g * npg + p * per;
    float a0 = 0.f, a1 = 0.f, a2 = 0.f;
    int n0 = 0, n1 = 0, n2 = 0;
    for (int i = 0; i < per; ++i) {
        int node = base + i;
        float v = bfs(h[(size_t)node * 128 + j]);
        int c = cluster[node];
        if (c == 0)      { a0 += v; n0++; }
        else if (c == 1) { a1 += v; n1++; }
        else             { a2 += v; n2++; }
    }
    size_t o = (size_t)blk * 3 * 128 + j;
    part_sums[o]       = a0;
    part_sums[o + 128] = a1;
    part_sums[o + 256] = a2;
    if (j == 0) {
        part_cnts[blk * 3 + 0] = n0;
        part_cnts[blk * 3 + 1] = n1;
        part_cnts[blk * 3 + 2] = n2;
    }
}

__global__ void head_kernel(const float* __restrict__ part_sums,
                            const int* __restrict__ part_cnts,
                            const float* __restrict__ Wl, const float* __restrict__ bl,
                            float* __restrict__ out) {
    int b = blockIdx.x, t = threadIdx.x;
    float s0 = 0.f, s1 = 0.f, s2 = 0.f;
    int n0 = 0, n1 = 0, n2 = 0;
#pragma unroll
    for (int p = 0; p < NPARTS; ++p) {
        int blk = b * NPARTS + p;
        size_t o = (size_t)blk * 3 * 128 + t;
        s0 += part_sums[o];
        s1 += part_sums[o + 128];
        s2 += part_sums[o + 256];
        n0 += part_cnts[blk * 3 + 0];
        n1 += part_cnts[blk * 3 + 1];
        n2 += part_cnts[blk * 3 + 2];
    }
    float z = s0 * (1.0f / fmaxf((float)n0, 1.0f)) * Wl[t]
            + s1 * (1.0f / fmaxf((float)n1, 1.0f)) * Wl[128 + t]
            + s2 * (1.0f / fmaxf((float)n2, 1.0f)) * Wl[256 + t];
    for (int off = 32; off > 0; off >>= 1) z += __shfl_down(z, off);
    __shared__ float partial[2];
    if ((t & 63) == 0) partial[t >> 6] = z;
    __syncthreads();
    if (t == 0) {
        float zz = partial[0] + partial[1] + bl[0];
        out[b] = 1.0f / (1.0f + expf(-zz));
    }
}

// ---------------- host ----------------

extern "C" void kernel_launch(void* const* d_in, const int* in_sizes, int n_in,
                              void* d_out, int out_size, void* d_ws, size_t ws_size,
                              hipStream_t stream) {
    const float* x  = (const float*)d_in[0];
    const int*   ei = (const int*)d_in[1];
    const float* W1 = (const float*)d_in[3];
    const float* b1 = (const float*)d_in[4];
    const float* W2 = (const float*)d_in[5];
    const float* b2 = (const float*)d_in[6];
    const float* W3 = (const float*)d_in[7];
    const float* b3 = (const float*)d_in[8];
    const float* Wl = (const float*)d_in[9];
    const float* bl = (const float*)d_in[10];
    float* out = (float*)d_out;

    const int N = in_sizes[0] / 128;        // 100000
    const int E = in_sizes[1] / 2;          // 600000
    const int B = out_size;                 // 250
    const int Npad = (N + 127) & ~127;      // 100096
    const int npg = N / B;                  // 400

    const int* srcp = ei;
    const int* dstp = ei + E;

    char* ws = (char*)d_ws;
    size_t off = 0;
    auto alloc = [&](size_t bytes) -> char* {
        char* p = ws + off;
        off += (bytes + 255) & ~(size_t)255;
        return p;
    };
    unsigned short* hb  = (unsigned short*)alloc((size_t)Npad * 128 * 2); // bf16 h
    unsigned short* ab  = (unsigned short*)alloc((size_t)Npad * 128 * 2); // bf16 agg out
    unsigned short* wt  = (unsigned short*)alloc((size_t)3 * 16384 * 2);  // Wt bf16 x3
    float* dinv    = (float*)alloc((size_t)N * 4);
    int*   cnt     = (int*)  alloc((size_t)N * 4);
    int*   fill    = (int*)  alloc((size_t)N * 4);
    int*   row_ptr = (int*)  alloc((size_t)N * 4);
    int*   cluster = (int*)  alloc((size_t)N * 4);
    int*   order   = (int*)  alloc((size_t)N * 4);
    int2*  ce      = (int2*) alloc((size_t)E * 8);
    int*   bsums   = (int*)  alloc(512 * 4);
    int*   degcnt  = (int*)  alloc(64 * 4);
    int*   degbase = (int*)  alloc(64 * 4);
    int*   degfill = (int*)  alloc(64 * 4);
    float* psums   = (float*)alloc((size_t)B * NPARTS * 3 * 128 * 4);
    int*   pcnts   = (int*)  alloc((size_t)B * NPARTS * 3 * 4);
    (void)ws_size; (void)n_in;

    hipMemsetAsync(cnt,     0, (size_t)N * 4, stream);
    hipMemsetAsync(fill,    0, (size_t)N * 4, stream);
    hipMemsetAsync(degcnt,  0, 64 * 4, stream);
    hipMemsetAsync(degfill, 0, 64 * 4, stream);

    count_kernel<<<(E + 255) / 256, 256, 0, stream>>>(dstp, cnt, E);
    prep_kernel<<<(N * 32 + 255) / 256, 256, 0, stream>>>(x, (unsigned*)hb, cnt,
                                                          dinv, cluster, N * 32);
    wtrans3<<<192, 256, 0, stream>>>(W1, W2, W3, wt);

    int nb256 = (N + 255) / 256;
    deghist<<<nb256, 256, 0, stream>>>(cnt, degcnt, N);
    degscan<<<1, 64, 0, stream>>>(degcnt, degbase);
    order_kernel<<<nb256, 256, 0, stream>>>(cnt, degbase, degfill, order, N);

    int scanBlocks = (N + 1023) / 1024;
    scan_block<<<scanBlocks, 256, 0, stream>>>(cnt, row_ptr, bsums, N);
    scan_bsums<<<1, 256, 0, stream>>>(bsums, scanBlocks);
    scan_add<<<scanBlocks, 256, 0, stream>>>(row_ptr, bsums, N);

    fill_kernel<<<(E + 255) / 256, 256, 0, stream>>>(srcp, dstp, row_ptr, fill,
                                                     ce, dinv, E);

    int gemmBlocks = Npad / 128;            // 782
    int aggBlocks = (N + 15) / 16;          // 6250

    agg_kernel<<<aggBlocks, 256, 0, stream>>>((const uint4*)hb, (uint4*)ab,
                                              row_ptr, cnt, ce, dinv, order, N);
    gemm_mfma<<<gemmBlocks, 256, 0, stream>>>(ab, wt, b1, hb, 1);
    agg_kernel<<<aggBlocks, 256, 0, stream>>>((const uint4*)hb, (uint4*)ab,
                                              row_ptr, cnt, ce, dinv, order, N);
    gemm_mfma<<<gemmBlocks, 256, 0, stream>>>(ab, wt + 16384, b2, hb, 1);
    agg_kernel<<<aggBlocks, 256, 0, stream>>>((const uint4*)hb, (uint4*)ab,
                                              row_ptr, cnt, ce, dinv, order, N);
    gemm_mfma<<<gemmBlocks, 256, 0, stream>>>(ab, wt + 32768, b3, hb, 0);

    pool_part<<<B * NPARTS, 128, 0, stream>>>(hb, cluster, psums, pcnts, npg);
    head_kernel<<<B, 128, 0, stream>>>(psums, pcnts, Wl, bl, out);
}

// Round 7
// 337.120 us; speedup vs baseline: 1.1452x; 1.1452x over previous
//
#include <hip/hip_runtime.h>
#include <hip/hip_bf16.h>
#include <math.h>

// N=100000 nodes, E=600000 edges, F=H=128, B=250 graphs, 400 nodes/graph.
//
// Pipeline (all h interfaces bf16, fp32 accumulation):
//   count -> prep (x->bf16 + dinv + cluster) -> scan -> fill (CSR (col,w) int2)
//   3x { agg: ab = (D^-1/2 (A+I) D^-1/2) hb   (4 nodes/wave, unroll-4 gathers)
//        gemm_mfma: hb = [relu](ab @ W + b)   (swapped-operand MFMA, direct stores) }
//   pool_part (16 partials/graph, bf16 reads) + head
//
// R1: pool 113us @5% occ -> 16 partials/graph. 671->572.
// R2: agg gather-byte bound -> bf16 gathers.
// R3: fp32 SIMT gemm 126us -> MFMA bf16, bf16-only h. 688->436.
// R4: agg 4 nodes/wave + edge weights; gemm LDS-staged Wt. 436->354.
// R5: degree-bucket ordering REGRESSED (WRITE 25->68MB scatter): reverted.
//     Kept+deepened the win: unroll-4 in-flight gathers (depth 1->2 gave 1.7x).
// R6: gemm epilogue rebuilt: swap MFMA operands so D gives 4 consecutive cols
//     per lane -> direct uint2 stores, no LDS staging/barriers for output.

#define WAVE 64
#define NPARTS 16
#define WPAD 136   // padded LDS row stride (ushorts) for conflict-free ds_read_b128

typedef __attribute__((ext_vector_type(8))) short bf16x8;
typedef __attribute__((ext_vector_type(4))) float f32x4;

__device__ __forceinline__ float bflo(unsigned u) { return __uint_as_float(u << 16); }
__device__ __forceinline__ float bfhi(unsigned u) { return __uint_as_float(u & 0xffff0000u); }
__device__ __forceinline__ float bfs(unsigned short s) {
    return __uint_as_float(((unsigned)s) << 16);
}
__device__ __forceinline__ unsigned short bf16r(float f) {
    unsigned u = __float_as_uint(f);
    return (unsigned short)((u + 0x7fffu + ((u >> 16) & 1u)) >> 16);
}
__device__ __forceinline__ unsigned pack_bf16(float a, float b) {
    return (unsigned)bf16r(a) | ((unsigned)bf16r(b) << 16);
}
__device__ __forceinline__ void fma8(float* acc, float w, uint4 u) {
    acc[0] += w * bflo(u.x); acc[1] += w * bfhi(u.x);
    acc[2] += w * bflo(u.y); acc[3] += w * bfhi(u.y);
    acc[4] += w * bflo(u.z); acc[5] += w * bfhi(u.z);
    acc[6] += w * bflo(u.w); acc[7] += w * bfhi(u.w);
}

// ---------------- CSR build ----------------

__global__ void count_kernel(const int* __restrict__ dst, int* __restrict__ cnt, int ne) {
    int e = blockIdx.x * blockDim.x + threadIdx.x;
    if (e < ne) atomicAdd(&cnt[dst[e]], 1);
}

// fused: x -> bf16, plus per-row dinv and cluster (one pass over x)
__global__ void prep_kernel(const float* __restrict__ x, unsigned* __restrict__ hb,
                            const int* __restrict__ cnt, float* __restrict__ dinv,
                            int* __restrict__ cluster, int n32) {
    int i = blockIdx.x * blockDim.x + threadIdx.x;   // handles 4 floats
    if (i >= n32) return;
    float4 v = ((const float4*)x)[i];
    hb[i * 2 + 0] = pack_bf16(v.x, v.y);
    hb[i * 2 + 1] = pack_bf16(v.z, v.w);
    if ((i & 31) == 31) {                            // floats 124..127 of this row
        int row = i >> 5;
        dinv[row] = rsqrtf((float)(cnt[row] + 1));
        cluster[row] = (int)(v.w + 2.0f * v.z + 0.5f);
    }
}

// exclusive scan of cnt -> row_ptr, 1024 elements per block
__global__ void scan_block(const int* __restrict__ in, int* __restrict__ out,
                           int* __restrict__ bsums, int n) {
    __shared__ int lds[256];
    int t = threadIdx.x;
    int base = blockIdx.x * 1024 + t * 4;
    int v0 = (base + 0 < n) ? in[base + 0] : 0;
    int v1 = (base + 1 < n) ? in[base + 1] : 0;
    int v2 = (base + 2 < n) ? in[base + 2] : 0;
    int v3 = (base + 3 < n) ? in[base + 3] : 0;
    int s = v0 + v1 + v2 + v3;
    lds[t] = s;
    __syncthreads();
    for (int off = 1; off < 256; off <<= 1) {
        int add = (t >= off) ? lds[t - off] : 0;
        __syncthreads();
        lds[t] += add;
        __syncthreads();
    }
    int excl = lds[t] - s;
    if (base + 0 < n) out[base + 0] = excl;
    if (base + 1 < n) out[base + 1] = excl + v0;
    if (base + 2 < n) out[base + 2] = excl + v0 + v1;
    if (base + 3 < n) out[base + 3] = excl + v0 + v1 + v2;
    if (t == 255) bsums[blockIdx.x] = lds[255];
}

__global__ void scan_bsums(int* __restrict__ bsums, int nb) {
    __shared__ int lds[256];
    int t = threadIdx.x;
    int v = (t < nb) ? bsums[t] : 0;
    lds[t] = v;
    __syncthreads();
    for (int off = 1; off < 256; off <<= 1) {
        int add = (t >= off) ? lds[t - off] : 0;
        __syncthreads();
        lds[t] += add;
        __syncthreads();
    }
    if (t < nb) bsums[t] = lds[t] - v;   // exclusive
}

__global__ void scan_add(int* __restrict__ out, const int* __restrict__ bsums, int n) {
    int base = blockIdx.x * 1024 + threadIdx.x * 4;
    int add = bsums[blockIdx.x];
#pragma unroll
    for (int i = 0; i < 4; ++i)
        if (base + i < n) out[base + i] += add;
}

// CSR fill with precomputed edge weight: ce[pos] = (src, dinv[src]*dinv[dst])
__global__ void fill_kernel(const int* __restrict__ src, const int* __restrict__ dst,
                            const int* __restrict__ row_ptr, int* __restrict__ fill,
                            int2* __restrict__ ce, const float* __restrict__ dinv,
                            int ne) {
    int e = blockIdx.x * blockDim.x + threadIdx.x;
    if (e < ne) {
        int d = dst[e], s = src[e];
        int pos = row_ptr[d] + atomicAdd(&fill[d], 1);
        ce[pos] = make_int2(s, __float_as_int(dinv[s] * dinv[d]));
    }
}

// ---------------- aggregation: 4 nodes/wave, unroll-4 pipelined gathers ----------
// out[n][:] = dinv[n]^2 * hb[n][:] + sum_{(s,w) in CSR(n)} w * hb[s][:]

__global__ void agg_kernel(const uint4* __restrict__ hb4, uint4* __restrict__ out4,
                           const int* __restrict__ row_ptr, const int* __restrict__ cnt,
                           const int2* __restrict__ ce, const float* __restrict__ dinv,
                           int n) {
    int wid = blockIdx.x * (blockDim.x >> 6) + (threadIdx.x >> 6);
    int lane = threadIdx.x & 63;
    int g = lane >> 4, sl = lane & 15;     // group (node slot) and sublane
    int node = wid * 4 + g;
    bool ok = node < n;
    int nc = ok ? node : (n - 1);
    float di = dinv[nc];
    uint4 self = hb4[(size_t)nc * 16 + sl];
    float w0 = di * di;
    float acc[8];
    acc[0] = w0 * bflo(self.x); acc[1] = w0 * bfhi(self.x);
    acc[2] = w0 * bflo(self.y); acc[3] = w0 * bfhi(self.y);
    acc[4] = w0 * bflo(self.z); acc[5] = w0 * bfhi(self.z);
    acc[6] = w0 * bflo(self.w); acc[7] = w0 * bfhi(self.w);
    int s0 = row_ptr[nc];
    int deg = ok ? cnt[nc] : 0;
    int2 c0, c1, c2, c3;
    if (deg > 0) {
        int dm = deg - 1;
        c0 = ce[s0];
        c1 = ce[s0 + min(1, dm)];
        c2 = ce[s0 + min(2, dm)];
        c3 = ce[s0 + min(3, dm)];
    }
    for (int i = 0; i < deg; i += 4) {
        int2 p0 = c0, p1 = c1, p2 = c2, p3 = c3;
        int nx = i + 4;
        if (nx < deg) {                      // prefetch next quad
            int dm = deg - 1;
            c0 = ce[s0 + nx];
            c1 = ce[s0 + min(nx + 1, dm)];
            c2 = ce[s0 + min(nx + 2, dm)];
            c3 = ce[s0 + min(nx + 3, dm)];
        }
        uint4 u0 = hb4[(size_t)p0.x * 16 + sl];   // 4 gathers in flight
        uint4 u1 = hb4[(size_t)p1.x * 16 + sl];
        uint4 u2 = hb4[(size_t)p2.x * 16 + sl];
        uint4 u3 = hb4[(size_t)p3.x * 16 + sl];
        float w1 = (i + 1 < deg) ? __int_as_float(p1.y) : 0.f;
        float w2 = (i + 2 < deg) ? __int_as_float(p2.y) : 0.f;
        float w3 = (i + 3 < deg) ? __int_as_float(p3.y) : 0.f;
        fma8(acc, __int_as_float(p0.y), u0);
        fma8(acc, w1, u1);
        fma8(acc, w2, u2);
        fma8(acc, w3, u3);
    }
    if (ok) {
        uint4 o;
        o.x = pack_bf16(acc[0], acc[1]);
        o.y = pack_bf16(acc[2], acc[3]);
        o.z = pack_bf16(acc[4], acc[5]);
        o.w = pack_bf16(acc[6], acc[7]);
        out4[(size_t)node * 16 + sl] = o;
    }
}

// ---------------- MFMA bf16 GEMM (swapped operands): Cb = [relu](A @ W + b) --------
// mfma(arg0=Wt-frag, arg1=A-frag): D[i][j] = sum_k Wt[n0+i][k] * A[m0+j][k]
//   = C[m0+j][n0+i].  D layout: lane(quad,lr) reg r -> C[m0+lr][n0+quad*4+r].
// => each lane holds 4 CONSECUTIVE output columns of one row: direct uint2 store.
// Wt staged once per block in LDS (padded); no output LDS, no post-MFMA barriers.

__global__ __launch_bounds__(256) void gemm_mfma(const unsigned short* __restrict__ A,
                                                 const unsigned short* __restrict__ Wt,
                                                 const float* __restrict__ bias,
                                                 unsigned short* __restrict__ Cb,
                                                 int relu) {
    __shared__ unsigned short sm[128 * WPAD];   // 34816 B (Wt only)
    const int t = threadIdx.x;
    const int wave = t >> 6, lane = t & 63;
    const int quad = lane >> 4, lr = lane & 15;
    const size_t row0 = (size_t)blockIdx.x * 128 + wave * 32;

    {   // stage Wt -> sm (row r = t>>1, half h = t&1)
        int r = t >> 1, h = t & 1;
        const uint4* s = (const uint4*)(Wt + r * 128 + h * 64);
        uint4* d = (uint4*)(sm + r * WPAD + h * 64);
#pragma unroll
        for (int i = 0; i < 8; ++i) d[i] = s[i];
    }
    __syncthreads();

    f32x4 acc[2][8];
#pragma unroll
    for (int i2 = 0; i2 < 2; ++i2)
#pragma unroll
        for (int ct = 0; ct < 8; ++ct) acc[i2][ct] = (f32x4){0.f, 0.f, 0.f, 0.f};

    const unsigned short* arow0 = A + (row0 + lr) * 128;
    const unsigned short* arow1 = arow0 + 16 * 128;
#pragma unroll
    for (int kc = 0; kc < 4; ++kc) {
        int kb = kc * 32 + quad * 8;
        bf16x8 a0 = *(const bf16x8*)(arow0 + kb);   // "B"-operand, m-tile 0
        bf16x8 a1 = *(const bf16x8*)(arow1 + kb);   // m-tile 1
#pragma unroll
        for (int ct = 0; ct < 8; ++ct) {
            bf16x8 w = *(const bf16x8*)(sm + (ct * 16 + lr) * WPAD + kb);
            acc[0][ct] = __builtin_amdgcn_mfma_f32_16x16x32_bf16(w, a0, acc[0][ct], 0, 0, 0);
            acc[1][ct] = __builtin_amdgcn_mfma_f32_16x16x32_bf16(w, a1, acc[1][ct], 0, 0, 0);
        }
    }

    // epilogue: bias + relu, pack 4 bf16 (consecutive cols) -> uint2 direct store
#pragma unroll
    for (int i2 = 0; i2 < 2; ++i2) {
        unsigned short* crow = Cb + (row0 + i2 * 16 + lr) * 128;
#pragma unroll
        for (int ct = 0; ct < 8; ++ct) {
            float4 bq = *(const float4*)&bias[ct * 16 + quad * 4];
            float v0 = acc[i2][ct][0] + bq.x;
            float v1 = acc[i2][ct][1] + bq.y;
            float v2 = acc[i2][ct][2] + bq.z;
            float v3 = acc[i2][ct][3] + bq.w;
            if (relu) {
                v0 = fmaxf(v0, 0.f); v1 = fmaxf(v1, 0.f);
                v2 = fmaxf(v2, 0.f); v3 = fmaxf(v3, 0.f);
            }
            uint2 p;
            p.x = pack_bf16(v0, v1);
            p.y = pack_bf16(v2, v3);
            *(uint2*)(crow + ct * 16 + quad * 4) = p;
        }
    }
}

// all 3 layers: W[k][n] fp32 -> Wt[n][k] bf16
__global__ void wtrans3(const float* __restrict__ W1, const float* __restrict__ W2,
                        const float* __restrict__ W3, unsigned short* __restrict__ Wt) {
    int idx = (blockIdx.x & 63) * 256 + threadIdx.x;   // 0..16383
    int layer = blockIdx.x >> 6;
    const float* W = (layer == 0) ? W1 : (layer == 1) ? W2 : W3;
    int n = idx >> 7, k = idx & 127;
    Wt[layer * 16384 + n * 128 + k] = bf16r(W[k * 128 + n]);
}

// ---------------- pooling: 16 partial blocks per graph, bf16 reads ----------------

__global__ void pool_part(const unsigned short* __restrict__ h,
                          const int* __restrict__ cluster,
                          float* __restrict__ part_sums, int* __restrict__ part_cnts,
                          int npg) {
    int blk = blockIdx.x;
    int g = blk / NPARTS, p = blk % NPARTS;
    int j = threadIdx.x;
    int per = npg / NPARTS;
    int base = g * npg + p * per;
    float a0 = 0.f, a1 = 0.f, a2 = 0.f;
    int n0 = 0, n1 = 0, n2 = 0;
    for (int i = 0; i < per; ++i) {
        int node = base + i;
        float v = bfs(h[(size_t)node * 128 + j]);
        int c = cluster[node];
        if (c == 0)      { a0 += v; n0++; }
        else if (c == 1) { a1 += v; n1++; }
        else             { a2 += v; n2++; }
    }
    size_t o = (size_t)blk * 3 * 128 + j;
    part_sums[o]       = a0;
    part_sums[o + 128] = a1;
    part_sums[o + 256] = a2;
    if (j == 0) {
        part_cnts[blk * 3 + 0] = n0;
        part_cnts[blk * 3 + 1] = n1;
        part_cnts[blk * 3 + 2] = n2;
    }
}

__global__ void head_kernel(const float* __restrict__ part_sums,
                            const int* __restrict__ part_cnts,
                            const float* __restrict__ Wl, const float* __restrict__ bl,
                            float* __restrict__ out) {
    int b = blockIdx.x, t = threadIdx.x;
    float s0 = 0.f, s1 = 0.f, s2 = 0.f;
    int n0 = 0, n1 = 0, n2 = 0;
#pragma unroll
    for (int p = 0; p < NPARTS; ++p) {
        int blk = b * NPARTS + p;
        size_t o = (size_t)blk * 3 * 128 + t;
        s0 += part_sums[o];
        s1 += part_sums[o + 128];
        s2 += part_sums[o + 256];
        n0 += part_cnts[blk * 3 + 0];
        n1 += part_cnts[blk * 3 + 1];
        n2 += part_cnts[blk * 3 + 2];
    }
    float z = s0 * (1.0f / fmaxf((float)n0, 1.0f)) * Wl[t]
            + s1 * (1.0f / fmaxf((float)n1, 1.0f)) * Wl[128 + t]
            + s2 * (1.0f / fmaxf((float)n2, 1.0f)) * Wl[256 + t];
    for (int off = 32; off > 0; off >>= 1) z += __shfl_down(z, off);
    __shared__ float partial[2];
    if ((t & 63) == 0) partial[t >> 6] = z;
    __syncthreads();
    if (t == 0) {
        float zz = partial[0] + partial[1] + bl[0];
        out[b] = 1.0f / (1.0f + expf(-zz));
    }
}

// ---------------- host ----------------

extern "C" void kernel_launch(void* const* d_in, const int* in_sizes, int n_in,
                              void* d_out, int out_size, void* d_ws, size_t ws_size,
                              hipStream_t stream) {
    const float* x  = (const float*)d_in[0];
    const int*   ei = (const int*)d_in[1];
    const float* W1 = (const float*)d_in[3];
    const float* b1 = (const float*)d_in[4];
    const float* W2 = (const float*)d_in[5];
    const float* b2 = (const float*)d_in[6];
    const float* W3 = (const float*)d_in[7];
    const float* b3 = (const float*)d_in[8];
    const float* Wl = (const float*)d_in[9];
    const float* bl = (const float*)d_in[10];
    float* out = (float*)d_out;

    const int N = in_sizes[0] / 128;        // 100000
    const int E = in_sizes[1] / 2;          // 600000
    const int B = out_size;                 // 250
    const int Npad = (N + 127) & ~127;      // 100096
    const int npg = N / B;                  // 400

    const int* srcp = ei;
    const int* dstp = ei + E;

    char* ws = (char*)d_ws;
    size_t off = 0;
    auto alloc = [&](size_t bytes) -> char* {
        char* p = ws + off;
        off += (bytes + 255) & ~(size_t)255;
        return p;
    };
    unsigned short* hb  = (unsigned short*)alloc((size_t)Npad * 128 * 2); // bf16 h
    unsigned short* ab  = (unsigned short*)alloc((size_t)Npad * 128 * 2); // bf16 agg out
    unsigned short* wt  = (unsigned short*)alloc((size_t)3 * 16384 * 2);  // Wt bf16 x3
    float* dinv    = (float*)alloc((size_t)N * 4);
    int*   cnt     = (int*)  alloc((size_t)N * 4);
    int*   fill    = (int*)  alloc((size_t)N * 4);
    int*   row_ptr = (int*)  alloc((size_t)N * 4);
    int*   cluster = (int*)  alloc((size_t)N * 4);
    int2*  ce      = (int2*) alloc((size_t)E * 8);
    int*   bsums   = (int*)  alloc(512 * 4);
    float* psums   = (float*)alloc((size_t)B * NPARTS * 3 * 128 * 4);
    int*   pcnts   = (int*)  alloc((size_t)B * NPARTS * 3 * 4);
    (void)ws_size; (void)n_in;

    hipMemsetAsync(cnt,  0, (size_t)N * 4, stream);
    hipMemsetAsync(fill, 0, (size_t)N * 4, stream);

    count_kernel<<<(E + 255) / 256, 256, 0, stream>>>(dstp, cnt, E);
    prep_kernel<<<(N * 32 + 255) / 256, 256, 0, stream>>>(x, (unsigned*)hb, cnt,
                                                          dinv, cluster, N * 32);
    wtrans3<<<192, 256, 0, stream>>>(W1, W2, W3, wt);

    int scanBlocks = (N + 1023) / 1024;
    scan_block<<<scanBlocks, 256, 0, stream>>>(cnt, row_ptr, bsums, N);
    scan_bsums<<<1, 256, 0, stream>>>(bsums, scanBlocks);
    scan_add<<<scanBlocks, 256, 0, stream>>>(row_ptr, bsums, N);

    fill_kernel<<<(E + 255) / 256, 256, 0, stream>>>(srcp, dstp, row_ptr, fill,
                                                     ce, dinv, E);

    int gemmBlocks = Npad / 128;            // 782
    int aggBlocks = (N + 15) / 16;          // 6250

    agg_kernel<<<aggBlocks, 256, 0, stream>>>((const uint4*)hb, (uint4*)ab,
                                              row_ptr, cnt, ce, dinv, N);
    gemm_mfma<<<gemmBlocks, 256, 0, stream>>>(ab, wt, b1, hb, 1);
    agg_kernel<<<aggBlocks, 256, 0, stream>>>((const uint4*)hb, (uint4*)ab,
                                              row_ptr, cnt, ce, dinv, N);
    gemm_mfma<<<gemmBlocks, 256, 0, stream>>>(ab, wt + 16384, b2, hb, 1);
    agg_kernel<<<aggBlocks, 256, 0, stream>>>((const uint4*)hb, (uint4*)ab,
                                              row_ptr, cnt, ce, dinv, N);
    gemm_mfma<<<gemmBlocks, 256, 0, stream>>>(ab, wt + 32768, b3, hb, 0);

    pool_part<<<B * NPARTS, 128, 0, stream>>>(hb, cluster, psums, pcnts, npg);
    head_kernel<<<B, 128, 0, stream>>>(psums, pcnts, Wl, bl, out);
}